// Round 15
// baseline (2566.048 us; speedup 1.0000x reference)
//
#include <hip/hip_runtime.h>
#include <hip/hip_bf16.h>
#include <stdint.h>

#define HD   512   // hidden dim H
#define ID   128   // input dim I
#define NCLS 100   // num classes
#define TT   512   // sequence length T
#define BB   128   // batch B
#define NEMB 101   // NC + 1 embedding rows
#define NGRP 16    // independent batch groups
#define GWG  16    // workgroups per group (sync clique)
#define RPG  8     // batch rows per group
#define COLS 32    // hidden cols per WG (GWG*COLS == HD)
#define THR  1024  // threads per recurrence WG (16 waves, 4 waves/SIMD)
#define CPAD 520   // LDS C row stride (mult of 4 -> float4-aligned; skews banks)
#define PST2 9     // partials stride in float2 units (odd -> bank-skewed)

// workspace layout (bytes)
#define WS_FLAG 0
#define WS_BAR  4096                   // uint bars[NGRP*512]: slot barrier
#define WS_G    65536                  // float G[101][2048]  (808 KB)
#define WS_C0   (1u * 1024 * 1024)     // float C0[128][512]  (256 KB)
#define WS_C1   (WS_C0 + 262144)       // float C1[128][512]  (256 KB)
#define WS_HFB  (WS_C1 + 262144)       // float Hfb[128][512] (256 KB)
#define NBAR    (NGRP * 512)           // 8192 uints (32 KB)

using bf16 = __hip_bfloat16;

__device__ __forceinline__ float b2f(bf16 v) { return __bfloat162float(v); }
__device__ __forceinline__ float sigf(float x) { return 1.0f / (1.0f + expf(-x)); }

// IF-scope (sc1) accessors — the only cross-WG primitives used; proven r6-r13.
__device__ __forceinline__ float cld(const float* p) {
    return __hip_atomic_load(p, __ATOMIC_RELAXED, __HIP_MEMORY_SCOPE_AGENT);
}
__device__ __forceinline__ void cst(float* p, float v) {
    __hip_atomic_store(p, v, __ATOMIC_RELAXED, __HIP_MEMORY_SCOPE_AGENT);
}
__device__ __forceinline__ unsigned cld_u(const unsigned* p) {
    return __hip_atomic_load(p, __ATOMIC_RELAXED, __HIP_MEMORY_SCOPE_AGENT);
}
__device__ __forceinline__ void cst_u(unsigned* p, unsigned v) {
    __hip_atomic_store(p, v, __ATOMIC_RELAXED, __HIP_MEMORY_SCOPE_AGENT);
}

template <bool BF>
__device__ __forceinline__ float ldv(const void* p, int i) {
    if constexpr (BF) return b2f(((const bf16*)p)[i]);
    else              return ((const float*)p)[i];
}

// ---------------------------------------------------------------------------
// Slot barrier (r15): arrive = relaxed sc1 STORE of own monotone count to own
// 128B-spaced slot — no RMW, so 16 arrivals don't serialize at the IF like
// r13's single-counter atomicAdd chain. Wait = wave 0 lanes 0..15 read all 16
// slots in ONE wave instruction, __ballot until all >= target. The leading
// __syncthreads drains every wave's sc1 C stores (vmcnt(0)) before the
// arrive store issues — same release ordering proven in r6-r13.
// ---------------------------------------------------------------------------
__device__ __forceinline__ void sbarrier(unsigned* slots, int rank, unsigned* c) {
    __syncthreads();
    const unsigned tgt = ++(*c);
    const int t = threadIdx.x;
    if (t < 64) {
        if (t == 0) cst_u(slots + rank * 32, tgt);
        unsigned v = tgt;
        do {
            if (t < GWG) v = cld_u(slots + t * 32);
        } while (__ballot(v < tgt) != 0ull);
    }
    __syncthreads();
}

// ---------------------------------------------------------------------------
// Dtype sniffer + slot zeroing. emb row 0 is exactly 0.0 by construction:
// bytes [256,512) are zero iff f32 (row 0) and nonzero iff bf16 (row 1).
// ---------------------------------------------------------------------------
__global__ void init_k(const uint32_t* __restrict__ emb_raw,
                       int* __restrict__ flag, unsigned int* __restrict__ bars) {
    const int t = threadIdx.x;
    for (int k = t; k < NBAR; k += 1024) bars[k] = 0u;
    if (t == 0) {
        uint32_t acc = 0;
        for (int i = 64; i < 128; ++i) acc |= emb_raw[i];
        *flag = (acc == 0u) ? 0 : 1;
    }
}

// ---------------------------------------------------------------------------
// G[c][j]: input-side gate pre-activations per class. j = q*512 + col,
// q in {0:f, 1:i, 2:o, 3:ctilde}; ctilde quarter pre-sigmoided.
// ---------------------------------------------------------------------------
template <bool BF>
__global__ void build_G(const int* __restrict__ flag,
                        const void* __restrict__ emb,
                        const void* __restrict__ Wfx, const void* __restrict__ Wix,
                        const void* __restrict__ Wox, const void* __restrict__ Wcx,
                        const void* __restrict__ bfv, const void* __restrict__ biv,
                        const void* __restrict__ bov, const void* __restrict__ bcv,
                        float* __restrict__ G) {
    if (*flag != (BF ? 1 : 0)) return;
    const int c   = blockIdx.x;
    const int j   = blockIdx.y * 256 + threadIdx.x;
    const int q   = j >> 9;
    const int col = j & 511;
    const void* W  = (q == 0) ? Wfx : (q == 1) ? Wix : (q == 2) ? Wox : Wcx;
    const void* bv = (q == 0) ? bfv : (q == 1) ? biv : (q == 2) ? bov : bcv;
    float acc = ldv<BF>(bv, col);
    for (int i = 0; i < ID; ++i)
        acc += ldv<BF>(emb, c * ID + i) * ldv<BF>(W, i * HD + col);
    if (q == 3) acc = sigf(acc);
    G[c * 2048 + j] = acc;
}

// ---------------------------------------------------------------------------
// Batch-split recurrence, 16 groups x 16 WGs x 32 cols (r12/r13 structure).
// Thread t: col = t&31, chunk = t>>5 (32 chunks x 16 h'), both gates:
// 32 pinned regs (proven no-spill). Per step: [prefetch G] stage C(t)
// (4 sc1 loads/thread) -> sync -> both-gate dot (2-way-broadcast b128 LDS
// reads, 256 FMA/thread) -> float2 partials -> sync -> 256 update threads
// (gates, own C in Creg, sc1-store) -> SLOT barrier.
// Epilogue (r15 FIX): o-gate dots Woc against C1 = C_{T-1} — the reference
// computes o from the PRE-update C at the final step. Using post-update C_T
// (r4-r13) was a real numerical bug: absmax jumped 0.03125 -> 0.125 exactly
// at r4 when the epilogue moved after the loop. TT-1 odd => the final step's
// input buffer is always C1, and the final update writes C0, leaving C1
// intact. h = tanh(C_T) * o with C_T in Creg.
// ---------------------------------------------------------------------------
template <bool BF>
__global__ __launch_bounds__(THR, 1) void recur_bs(
    const int* __restrict__ flag, const int* __restrict__ x,
    const float* __restrict__ G,
    const void* __restrict__ Wfc, const void* __restrict__ Wic,
    const void* __restrict__ Woc,
    float* __restrict__ C0, float* __restrict__ C1,
    float* __restrict__ Hfb, unsigned int* __restrict__ bars)
{
    if (*flag != (BF ? 1 : 0)) return;

    __shared__ __align__(16) float Cs[RPG * CPAD];     // 16.6 KB
    __shared__ __align__(8)  float2 part2[THR * PST2]; // 73.7 KB
    __shared__ int   idx[RPG * TT];                    // 16 KB
    __shared__ int   lz[RPG];

    const int blk   = blockIdx.x;
    const int grp   = blk >> 4;           // 0..15
    const int rank  = blk & 15;           // 0..15
    const int r0    = grp * RPG;
    const int h0    = rank * COLS;
    const int tid   = threadIdx.x;
    const int col   = tid & 31;
    const int chunk = tid >> 5;           // 0..31 (16 h' each)
    unsigned* slots = bars + grp * 512;   // 16 slots, 128 B apart

    // ---- stage x rows (4096 ints, flat-contiguous), find group start ----
    #pragma unroll
    for (int k = 0; k < 4; ++k)
        idx[tid + 1024 * k] = x[r0 * TT + tid + 1024 * k];
    if (tid < RPG) lz[tid] = -1;
    __syncthreads();
    if (tid < TT)
        #pragma unroll
        for (int r = 0; r < RPG; ++r)
            if (idx[r * TT + tid] == 0) atomicMax(&lz[r], tid);
    __syncthreads();
    int t0 = TT;
    #pragma unroll
    for (int r = 0; r < RPG; ++r) t0 = min(t0, lz[r] + 1);

    // ---- 32 pinned register weights: BOTH gates, own col, own 16-h' chunk
    float wf[16], wi[16];
    {
        #pragma unroll
        for (int k = 0; k < 16; ++k) {
            wf[k] = ldv<BF>(Wfc, (chunk * 16 + k) * HD + h0 + col);
            wi[k] = ldv<BF>(Wic, (chunk * 16 + k) * HD + h0 + col);
        }
        #pragma unroll
        for (int k = 0; k < 16; ++k)
            asm volatile("" : "+v"(wf[k]), "+v"(wi[k]));
    }

    // ---- zero own C slices in both buffers (coherent stores) ----
    if (tid < COLS * RPG) {
        const int c = tid & 31, r = tid >> 5;
        cst(&C0[(r0 + r) * HD + h0 + c], 0.0f);
        cst(&C1[(r0 + r) * HD + h0 + c], 0.0f);
    }
    unsigned bc = 0;
    sbarrier(slots, rank, &bc);           // zeros visible group-wide

    float Creg = 0.0f;                    // update threads' own C element
    const int erow = tid >> 7;            // stage: row 0..7
    const int eh4  = (tid & 127) * 4;     // stage: h' base (4 consecutive)
    const bool isUpd = (tid < COLS * RPG);
    const int uc = tid & 31, ur = tid >> 5;   // update thread's (col, row)

    for (int t = t0; t < TT; ++t) {
        const float* cur = (t & 1) ? C1 : C0;
        float*       nxt = (t & 1) ? C0 : C1;

        // ---- prefetch G gate operands for the update (overlaps the dot) --
        float gf = 0.f, gi = 0.f, sgc = 0.f;
        int cl = 1;
        if (isUpd) {
            cl = idx[ur * TT + t];
            const float* Gr = G + cl * 2048;
            gf  = Gr[h0 + uc];
            gi  = Gr[512 + h0 + uc];
            sgc = Gr[1536 + h0 + uc];
        }

        // ---- stage C(t): 4 consecutive floats of row erow at h'=eh4 ----
        {
            const float* cb = cur + (r0 + erow) * HD + eh4;
            const float v0 = cld(cb);
            const float v1 = cld(cb + 1);
            const float v2 = cld(cb + 2);
            const float v3 = cld(cb + 3);
            float* cs = Cs + erow * CPAD + eh4;
            cs[0] = v0; cs[1] = v1; cs[2] = v2; cs[3] = v3;
        }
        __syncthreads();

        // ---- both-gate dot over 16 h' (2-way broadcast LDS reads) ----
        float accf[RPG], acci[RPG];
        #pragma unroll
        for (int r = 0; r < RPG; ++r) { accf[r] = 0.0f; acci[r] = 0.0f; }
        {
            const int cb4 = chunk * 4;    // float4 index of chunk base
            #pragma unroll
            for (int j = 0; j < 4; ++j) {
                const float f0 = wf[4*j], f1 = wf[4*j+1], f2 = wf[4*j+2], f3 = wf[4*j+3];
                const float i0 = wi[4*j], i1 = wi[4*j+1], i2 = wi[4*j+2], i3 = wi[4*j+3];
                #pragma unroll
                for (int r = 0; r < RPG; ++r) {
                    const float4 cv = reinterpret_cast<const float4*>(
                        Cs + r * CPAD)[cb4 + j];
                    accf[r] += f0*cv.x + f1*cv.y + f2*cv.z + f3*cv.w;
                    acci[r] += i0*cv.x + i1*cv.y + i2*cv.z + i3*cv.w;
                }
            }
        }
        {
            float2* pp = part2 + tid * PST2;
            #pragma unroll
            for (int r = 0; r < RPG; ++r)
                pp[r] = make_float2(accf[r], acci[r]);
        }
        __syncthreads();

        // ---- update: thread t<256 owns (col = uc, row = ur) ----
        if (isUpd) {
            float df = 0.f, di = 0.f;
            #pragma unroll
            for (int ch = 0; ch < 32; ++ch) {
                const float2 v = part2[(ch * 32 + uc) * PST2 + ur];
                df += v.x;
                di += v.y;
            }
            float Cn = sgc * sigf(gi + di) + Creg * sigf(gf + df);
            Cn = (cl > 0) ? Cn : 0.0f;
            Creg = Cn;
            cst(&nxt[(r0 + ur) * HD + h0 + uc], Cn);
        }
        sbarrier(slots, rank, &bc);
    }

    // ---- o-gate + h once. o uses C_{T-1} = C1 (pre-update at final step) --
    {
        const float* cb = C1 + (r0 + erow) * HD + eh4;
        const float v0 = cld(cb);
        const float v1 = cld(cb + 1);
        const float v2 = cld(cb + 2);
        const float v3 = cld(cb + 3);
        float* cs = Cs + erow * CPAD + eh4;
        cs[0] = v0; cs[1] = v1; cs[2] = v2; cs[3] = v3;
        __syncthreads();

        // thread = (col, chunk of 16 h') for the o-gate dot
        float ao[RPG];
        #pragma unroll
        for (int r = 0; r < RPG; ++r) ao[r] = 0.0f;
        #pragma unroll 4
        for (int k = 0; k < 16; ++k) {
            const int hp = chunk * 16 + k;
            const float wo = ldv<BF>(Woc, hp * HD + h0 + col);
            #pragma unroll
            for (int r = 0; r < RPG; ++r)
                ao[r] += wo * Cs[r * CPAD + hp];
        }
        {
            float2* pp = part2 + tid * PST2;
            #pragma unroll
            for (int r2 = 0; r2 < RPG / 2; ++r2)
                pp[r2] = make_float2(ao[2 * r2], ao[2 * r2 + 1]);
        }
        __syncthreads();
        if (isUpd) {
            float s = 0.f;
            #pragma unroll
            for (int ch = 0; ch < 32; ++ch) {
                const float2 v = part2[(ch * 32 + uc) * PST2 + (ur >> 1)];
                s += (ur & 1) ? v.y : v.x;
            }
            const int cl2 = idx[ur * TT + TT - 1];
            const float o = sigf(G[cl2 * 2048 + 1024 + h0 + uc] + s);
            Hfb[(r0 + ur) * HD + h0 + uc] = tanhf(Creg) * o;
        }
    }
}

// ---------------------------------------------------------------------------
// Projection + log_softmax, one WG per batch row.
// ---------------------------------------------------------------------------
template <bool BF>
__global__ __launch_bounds__(128) void proj(
    const int* __restrict__ flag, const float* __restrict__ Hfb,
    const void* __restrict__ Wph, const void* __restrict__ bp,
    void* __restrict__ out)
{
    if (*flag != (BF ? 1 : 0)) return;
    __shared__ __align__(16) float hv[HD];
    __shared__ float p_s[NCLS];
    __shared__ float lse_s;
    const int b   = blockIdx.x;
    const int tid = threadIdx.x;

    reinterpret_cast<float4*>(hv)[tid] =
        reinterpret_cast<const float4*>(Hfb + b * HD)[tid];
    __syncthreads();

    if (tid < NCLS) {
        float p = ldv<BF>(bp, tid);
        for (int h = 0; h < HD; ++h)
            p += hv[h] * ldv<BF>(Wph, h * NCLS + tid);
        p_s[tid] = p;
    }
    __syncthreads();
    if (tid == 0) {
        float m = -1e30f;
        for (int n = 0; n < NCLS; ++n) m = fmaxf(m, p_s[n]);
        float sum = 0.0f;
        for (int n = 0; n < NCLS; ++n) sum += expf(p_s[n] - m);
        lse_s = m + logf(sum);
    }
    __syncthreads();
    if (tid < NCLS) {
        const float v = p_s[tid] - lse_s;
        if constexpr (BF) ((bf16*)out)[b * NCLS + tid] = __float2bfloat16(v);
        else              ((float*)out)[b * NCLS + tid] = v;
    }
}

// ---------------------------------------------------------------------------
extern "C" void kernel_launch(void* const* d_in, const int* in_sizes, int n_in,
                              void* d_out, int out_size, void* d_ws, size_t ws_size,
                              hipStream_t stream) {
    const int*  x   = (const int*)d_in[0];
    const void* emb = d_in[1];
    const void* Wfx = d_in[2];
    const void* Wfc = d_in[3];
    const void* bfv = d_in[4];
    const void* Wix = d_in[5];
    const void* Wic = d_in[6];
    const void* biv = d_in[7];
    const void* Wox = d_in[8];
    const void* Woc = d_in[9];
    const void* bov = d_in[10];
    const void* Wcx = d_in[11];
    const void* bcv = d_in[12];
    const void* Wph = d_in[13];
    const void* bp  = d_in[14];

    int*          flag = (int*)((char*)d_ws + WS_FLAG);
    unsigned int* bars = (unsigned int*)((char*)d_ws + WS_BAR);
    float*        G    = (float*)((char*)d_ws + WS_G);
    float*        C0   = (float*)((char*)d_ws + WS_C0);
    float*        C1   = (float*)((char*)d_ws + WS_C1);
    float*        Hfb  = (float*)((char*)d_ws + WS_HFB);

    init_k<<<1, 1024, 0, stream>>>((const uint32_t*)emb, flag, bars);

    build_G<false><<<dim3(NEMB, 8), 256, 0, stream>>>(flag, emb, Wfx, Wix, Wox, Wcx,
                                                      bfv, biv, bov, bcv, G);
    build_G<true ><<<dim3(NEMB, 8), 256, 0, stream>>>(flag, emb, Wfx, Wix, Wox, Wcx,
                                                      bfv, biv, bov, bcv, G);

    {
        void* args[] = {(void*)&flag, (void*)&x, (void*)&G,
                        (void*)&Wfc, (void*)&Wic, (void*)&Woc,
                        (void*)&C0, (void*)&C1, (void*)&Hfb, (void*)&bars};
        hipLaunchCooperativeKernel((const void*)recur_bs<false>, dim3(NGRP * GWG), dim3(THR),
                                   args, 0, stream);
        hipLaunchCooperativeKernel((const void*)recur_bs<true>, dim3(NGRP * GWG), dim3(THR),
                                   args, 0, stream);
    }

    proj<false><<<BB, 128, 0, stream>>>(flag, Hfb, Wph, bp, d_out);
    proj<true ><<<BB, 128, 0, stream>>>(flag, Hfb, Wph, bp, d_out);
}